// Round 4
// baseline (1089.295 us; speedup 1.0000x reference)
//
#include <hip/hip_runtime.h>
#include <hip/hip_fp16.h>
#include <cstdint>
#include <cstddef>

#define NN 100000
#define NE 1600000
#define NEP (NE + NN)   // edges + self-loops = 1,700,000
#define SCAN_BLOCKS ((NN + 1023) / 1024)   // 98
#define XSTR 68         // padded stride for x (16-B aligned rows)

__device__ __forceinline__ float elu_f(float x) {
    return x > 0.f ? x : __expf(x) - 1.f;
}

// ================= CSR build (counting sort by dst) =================

__global__ __launch_bounds__(256) void count_deg(const int* __restrict__ ei, int* __restrict__ deg)
{
    int e = blockIdx.x * 256 + threadIdx.x;
    if (e >= NEP) return;
    int dst = (e < NE) ? ei[NE + e] : e - NE;
    atomicAdd(&deg[dst], 1);
}

__global__ __launch_bounds__(256) void scan_pass1(const int* __restrict__ deg, int* __restrict__ part)
{
    __shared__ int wsum[4];
    int t = threadIdx.x;
    int i0 = blockIdx.x * 1024 + t * 4;
    int s = 0;
    if (i0 + 3 < NN) { int4 d = *(const int4*)(deg + i0); s = d.x + d.y + d.z + d.w; }
    else {
        for (int k = 0; k < 4; k++) if (i0 + k < NN) s += deg[i0 + k];
    }
    for (int d = 1; d < 64; d <<= 1) s += __shfl_xor(s, d, 64);
    if ((t & 63) == 0) wsum[t >> 6] = s;
    __syncthreads();
    if (t == 0) part[blockIdx.x] = wsum[0] + wsum[1] + wsum[2] + wsum[3];
}

__global__ __launch_bounds__(128) void scan_pass2(int* __restrict__ part, int* __restrict__ off)
{
    __shared__ int wt[2];
    int t = threadIdx.x;
    int lane = t & 63, w = t >> 6;
    int v = (t < SCAN_BLOCKS) ? part[t] : 0;
    int x = v;
    for (int d = 1; d < 64; d <<= 1) { int y = __shfl_up(x, d, 64); if (lane >= d) x += y; }
    if (lane == 63) wt[w] = x;
    __syncthreads();
    int base = (w == 1) ? wt[0] : 0;
    int excl = base + x - v;
    if (t < SCAN_BLOCKS) part[t] = excl;
    if (t == SCAN_BLOCKS - 1) off[NN] = excl + v;
}

__global__ __launch_bounds__(256) void scan_pass3(const int* __restrict__ deg, const int* __restrict__ part,
                                                  int* __restrict__ off, int* __restrict__ cursor)
{
    __shared__ int wsum[4];
    int t = threadIdx.x, lane = t & 63, w = t >> 6;
    int i0 = blockIdx.x * 1024 + t * 4;
    int d0 = 0, d1 = 0, d2 = 0, d3 = 0;
    if (i0 + 3 < NN) { int4 d = *(const int4*)(deg + i0); d0 = d.x; d1 = d.y; d2 = d.z; d3 = d.w; }
    else if (i0 < NN) {
        d0 = deg[i0];
        if (i0 + 1 < NN) d1 = deg[i0 + 1];
        if (i0 + 2 < NN) d2 = deg[i0 + 2];
    }
    int s = d0 + d1 + d2 + d3;
    int x = s;
    for (int d = 1; d < 64; d <<= 1) { int y = __shfl_up(x, d, 64); if (lane >= d) x += y; }
    if (lane == 63) wsum[w] = x;
    __syncthreads();
    int wbase = 0;
    for (int i = 0; i < w; i++) wbase += wsum[i];
    int base = part[blockIdx.x] + wbase + x - s;
    if (i0 < NN)     { off[i0]     = base;                cursor[i0]     = base; }
    if (i0 + 1 < NN) { off[i0 + 1] = base + d0;           cursor[i0 + 1] = base + d0; }
    if (i0 + 2 < NN) { off[i0 + 2] = base + d0 + d1;      cursor[i0 + 2] = base + d0 + d1; }
    if (i0 + 3 < NN) { off[i0 + 3] = base + d0 + d1 + d2; cursor[i0 + 3] = base + d0 + d1 + d2; }
}

__global__ __launch_bounds__(256) void scatter_csr(const int* __restrict__ ei,
                                                   int* __restrict__ cursor, int* __restrict__ csr)
{
    int e = blockIdx.x * 256 + threadIdx.x;
    if (e >= NEP) return;
    int src, dst;
    if (e < NE) { src = ei[e]; dst = ei[NE + e]; } else { src = dst = e - NE; }
    int pos = atomicAdd(&cursor[dst], 1);
    csr[pos] = src;
}

// ================= node feature prep =================
// Register-resident; weights via wave-uniform reads (s_load), no LDS.
__global__ __launch_bounds__(256) void bio_kernel(
    const float* __restrict__ xb, const float* __restrict__ W1, const float* __restrict__ b1,
    const float* __restrict__ g0, const float* __restrict__ bb0,
    const float* __restrict__ m0, const float* __restrict__ v0,
    const float* __restrict__ W2, const float* __restrict__ b2,
    float* __restrict__ x)
{
    int i = blockIdx.x * 256 + threadIdx.x;
    if (i >= NN) return;
    float bio[64];
    const float4* p = (const float4*)(xb + (size_t)i * 64);
    #pragma unroll
    for (int q = 0; q < 16; q++) {
        float4 f = p[q];
        bio[q*4] = f.x; bio[q*4+1] = f.y; bio[q*4+2] = f.z; bio[q*4+3] = f.w;
    }
    float t1[16];
    #pragma unroll
    for (int j = 0; j < 16; j++) {
        float acc = b1[j];
        #pragma unroll
        for (int k = 0; k < 64; k++) acc += bio[k] * W1[j*64 + k];
        float s = g0[j] * rsqrtf(v0[j] + 1e-5f);
        acc = acc * s + (bb0[j] - m0[j] * s);
        t1[j] = elu_f(acc);
    }
    float* xo = x + (size_t)i * XSTR + 50;
    #pragma unroll
    for (int j = 0; j < 16; j++) {
        float acc = b2[j];
        #pragma unroll
        for (int k = 0; k < 16; k++) acc += t1[k] * W2[j*16 + k];
        xo[j] = elu_f(acc);
    }
}

__global__ __launch_bounds__(256) void copy_pca(const float* __restrict__ xp, float* __restrict__ x)
{
    int t = blockIdx.x * 256 + threadIdx.x;
    if (t >= NN * 50) return;
    int i = t / 50, j = t - i * 50;
    x[(size_t)i * XSTR + j] = xp[t];
}

// ================= register-row GEMM: out[n,DOUT] = in @ W^T + b =================
// Thread owns one node row in VGPRs. W/bias indices are wave-uniform -> s_load,
// inner loop is pure v_fmac (no LDS, no per-FMA VMEM).
template<int DIN, int DINPAD, int DOUT, int JCHUNK, bool HOUT>
__global__ __launch_bounds__(256) void gemm_reg(
    const float* __restrict__ in, const float* __restrict__ W,
    const float* __restrict__ bias, void* __restrict__ outv, int n)
{
    int i = blockIdx.x * 256 + threadIdx.x;
    if (i >= n) return;
    float row[DINPAD];
    const float4* p = (const float4*)(in + (size_t)i * DINPAD);
    #pragma unroll
    for (int q = 0; q < DINPAD / 4; q++) {
        float4 f = p[q];
        row[q*4] = f.x; row[q*4+1] = f.y; row[q*4+2] = f.z; row[q*4+3] = f.w;
    }
    #pragma unroll 1
    for (int jc = 0; jc < DOUT; jc += JCHUNK) {
        float acc[JCHUNK];
        #pragma unroll
        for (int jj = 0; jj < JCHUNK; jj++) acc[jj] = bias[jc + jj];
        #pragma unroll
        for (int k = 0; k < DIN; k++) {
            #pragma unroll
            for (int jj = 0; jj < JCHUNK; jj++)
                acc[jj] += row[k] * W[(jc + jj) * DIN + k];
        }
        if (HOUT) {
            __half* o = (__half*)outv + (size_t)i * DOUT + jc;
            #pragma unroll
            for (int jj = 0; jj < JCHUNK; jj += 2)
                *(__half2*)(o + jj) = __floats2half2_rn(acc[jj], acc[jj+1]);
        } else {
            float* o = (float*)outv + (size_t)i * DOUT + jc;
            #pragma unroll
            for (int jj = 0; jj < JCHUNK; jj++) o[jj] = acc[jj];
        }
    }
}

// ================= fused GATv2 layer 1: one wave per dst node (fp16 tables) =================
__global__ __launch_bounds__(256) void fused_gat1(
    const int* __restrict__ off, const int* __restrict__ csr,
    const __half* __restrict__ xl, const __half* __restrict__ xr,
    const float* __restrict__ att, const float* __restrict__ bias,
    const float* __restrict__ g, const float* __restrict__ b,
    const float* __restrict__ m, const float* __restrict__ v,
    float* __restrict__ h1)
{
    int wave = threadIdx.x >> 6;
    int lane = threadIdx.x & 63;
    int node = blockIdx.x * 4 + wave;
    if (node >= NN) return;
    int ch = lane * 2;

    float2 xrv = __half22float2(*(const __half2*)(xr + (size_t)node * 128 + ch));
    float2 av  = *(const float2*)(att + ch);

    int k0 = off[node], k1 = off[node + 1];
    float accx = 0.f, accy = 0.f, denom = 0.f;

    for (int base = k0; base < k1; base += 64) {
        int nb = min(64, k1 - base);
        int mysrc = (lane < nb) ? csr[base + lane] : 0;
        int src0 = __shfl(mysrc, 0, 64);
        __half2 hcur = *(const __half2*)(xl + (size_t)src0 * 128 + ch);
        for (int t = 0; t < nb; t++) {
            int tn = (t + 1 < nb) ? t + 1 : t;
            int srcn = __shfl(mysrc, tn, 64);
            __half2 hnxt = *(const __half2*)(xl + (size_t)srcn * 128 + ch);
            float2 xlv = __half22float2(hcur);
            float sx = xlv.x + xrv.x; sx = fmaxf(sx, 0.2f * sx);
            float sy = xlv.y + xrv.y; sy = fmaxf(sy, 0.2f * sy);
            float pp = sx * av.x + sy * av.y;
            pp += __shfl_xor(pp, 1, 64);
            pp += __shfl_xor(pp, 2, 64);
            pp += __shfl_xor(pp, 4, 64);
            pp += __shfl_xor(pp, 8, 64);
            float w = __expf(pp);
            denom += w;
            accx += xlv.x * w;
            accy += xlv.y * w;
            hcur = hnxt;
        }
    }
    float inv = 1.f / (denom + 1e-16f);
    float sX = g[ch]     * rsqrtf(v[ch]     + 1e-5f);
    float sY = g[ch + 1] * rsqrtf(v[ch + 1] + 1e-5f);
    float ox = accx * inv + bias[ch];
    float oy = accy * inv + bias[ch + 1];
    ox = ox * sX + (b[ch]     - m[ch]     * sX);
    oy = oy * sY + (b[ch + 1] - m[ch + 1] * sY);
    float2 o; o.x = elu_f(ox); o.y = elu_f(oy);
    *(float2*)(h1 + (size_t)node * 128 + ch) = o;
}

// ================= fused GATv2 layer 2: one wave per dst node (fp16 tables) =================
__global__ __launch_bounds__(256) void fused_gat2(
    const int* __restrict__ off, const int* __restrict__ csr,
    const __half* __restrict__ xl, const __half* __restrict__ xr,
    const float* __restrict__ att, const float* __restrict__ bias,
    const float* __restrict__ g, const float* __restrict__ b,
    const float* __restrict__ m, const float* __restrict__ v,
    float* __restrict__ h2)
{
    int wave = threadIdx.x >> 6;
    int lane = threadIdx.x & 63;
    int node = blockIdx.x * 4 + wave;
    if (node >= NN) return;
    int slot = lane >> 5;      // 0 or 1
    int c = lane & 31;

    float xrv = __half2float(xr[(size_t)node * 32 + c]);
    float attv = att[c];

    int k0 = off[node], k1 = off[node + 1];
    float acc = 0.f, denom = 0.f;

    for (int base = k0; base < k1; base += 64) {
        int nb = min(64, k1 - base);
        int mysrc = (lane < nb) ? csr[base + lane] : 0;
        for (int t = 0; t < nb; t += 2) {
            int idx = t + slot;
            bool valid = idx < nb;
            int src = __shfl(mysrc, valid ? idx : 0, 64);
            float xlv = __half2float(xl[(size_t)src * 32 + c]);
            float s = xlv + xrv; s = fmaxf(s, 0.2f * s);
            float pp = s * attv;
            pp += __shfl_xor(pp, 1, 64);
            pp += __shfl_xor(pp, 2, 64);
            pp += __shfl_xor(pp, 4, 64);
            pp += __shfl_xor(pp, 8, 64);
            pp += __shfl_xor(pp, 16, 64);
            float w = valid ? __expf(pp) : 0.f;
            denom += w;
            acc += xlv * w;
        }
    }
    acc   += __shfl_xor(acc, 32, 64);
    denom += __shfl_xor(denom, 32, 64);
    if (slot == 0) {
        float inv = 1.f / (denom + 1e-16f);
        float sC = g[c] * rsqrtf(v[c] + 1e-5f);
        float o = acc * inv + bias[c];
        o = o * sC + (b[c] - m[c] * sC);
        h2[(size_t)node * 32 + c] = elu_f(o);
    }
}

extern "C" void kernel_launch(void* const* d_in, const int* in_sizes, int n_in,
                              void* d_out, int out_size, void* d_ws, size_t ws_size,
                              hipStream_t stream)
{
    const float* x_pca = (const float*)d_in[0];
    const float* x_bio = (const float*)d_in[1];
    const int*   ei    = (const int*)d_in[2];
    const float* bioW1 = (const float*)d_in[3];
    const float* biob1 = (const float*)d_in[4];
    const float* bn0_g = (const float*)d_in[5];
    const float* bn0_b = (const float*)d_in[6];
    const float* bn0_m = (const float*)d_in[7];
    const float* bn0_v = (const float*)d_in[8];
    const float* bioW2 = (const float*)d_in[9];
    const float* biob2 = (const float*)d_in[10];
    const float* Wl1   = (const float*)d_in[11];
    const float* bl1   = (const float*)d_in[12];
    const float* Wr1   = (const float*)d_in[13];
    const float* br1   = (const float*)d_in[14];
    const float* att1  = (const float*)d_in[15];
    const float* bias1 = (const float*)d_in[16];
    const float* bn1_g = (const float*)d_in[17];
    const float* bn1_b = (const float*)d_in[18];
    const float* bn1_m = (const float*)d_in[19];
    const float* bn1_v = (const float*)d_in[20];
    const float* Wl2   = (const float*)d_in[21];
    const float* bl2   = (const float*)d_in[22];
    const float* Wr2   = (const float*)d_in[23];
    const float* br2   = (const float*)d_in[24];
    const float* att2  = (const float*)d_in[25];
    const float* bias2 = (const float*)d_in[26];
    const float* bn2_g = (const float*)d_in[27];
    const float* bn2_b = (const float*)d_in[28];
    const float* bn2_m = (const float*)d_in[29];
    const float* bn2_v = (const float*)d_in[30];
    const float* predW = (const float*)d_in[31];
    const float* predb = (const float*)d_in[32];

    float* ws = (float*)d_ws;
    float*  x    = ws;                                  // N*68   = 6,800,000 floats
    float*  h1   = x + (size_t)NN * XSTR;               // N*128  = 12,800,000 floats
    __half* xl1h = (__half*)(h1 + (size_t)NN * 128);    // N*128 halves
    __half* xr1h = xl1h + (size_t)NN * 128;             // N*128 halves
    __half* xl2h = xr1h + (size_t)NN * 128;             // N*32 halves
    __half* xr2h = xl2h + (size_t)NN * 32;              // N*32 halves
    float*  h2   = (float*)(xr2h + (size_t)NN * 32);    // N*32 floats
    int*    ibase  = (int*)(h2 + (size_t)NN * 32);
    int*    deg    = ibase;            // NN
    int*    off    = ibase + NN;       // NN+1
    int*    cursor = off + NN + 1;     // NN
    int*    part   = cursor + NN;      // 128
    int*    csr    = part + 128;       // NEP

    float* out = (float*)d_out;

    // ---- CSR build ----
    hipMemsetAsync(deg, 0, (size_t)NN * sizeof(int), stream);
    count_deg<<<(NEP + 255) / 256, 256, 0, stream>>>(ei, deg);
    scan_pass1<<<SCAN_BLOCKS, 256, 0, stream>>>(deg, part);
    scan_pass2<<<1, 128, 0, stream>>>(part, off);
    scan_pass3<<<SCAN_BLOCKS, 256, 0, stream>>>(deg, part, off, cursor);
    scatter_csr<<<(NEP + 255) / 256, 256, 0, stream>>>(ei, cursor, csr);

    // ---- node features ----
    bio_kernel<<<(NN + 255) / 256, 256, 0, stream>>>(
        x_bio, bioW1, biob1, bn0_g, bn0_b, bn0_m, bn0_v, bioW2, biob2, x);
    copy_pca<<<(NN * 50 + 255) / 256, 256, 0, stream>>>(x_pca, x);

    // ---- layer-1 transforms (fp16 out) ----
    gemm_reg<66, XSTR, 128, 8, true><<<(NN + 255) / 256, 256, 0, stream>>>(x, Wl1, bl1, xl1h, NN);
    gemm_reg<66, XSTR, 128, 8, true><<<(NN + 255) / 256, 256, 0, stream>>>(x, Wr1, br1, xr1h, NN);

    // ---- fused layer-1 edge phase + bias/BN/ELU ----
    fused_gat1<<<(NN + 3) / 4, 256, 0, stream>>>(
        off, csr, xl1h, xr1h, att1, bias1, bn1_g, bn1_b, bn1_m, bn1_v, h1);

    // ---- layer-2 transforms (fp16 out) ----
    gemm_reg<128, 128, 32, 8, true><<<(NN + 255) / 256, 256, 0, stream>>>(h1, Wl2, bl2, xl2h, NN);
    gemm_reg<128, 128, 32, 8, true><<<(NN + 255) / 256, 256, 0, stream>>>(h1, Wr2, br2, xr2h, NN);

    // ---- fused layer-2 edge phase + bias/BN/ELU ----
    fused_gat2<<<(NN + 3) / 4, 256, 0, stream>>>(
        off, csr, xl2h, xr2h, att2, bias2, bn2_g, bn2_b, bn2_m, bn2_v, h2);

    // ---- prediction head: Linear(32,50) ----
    gemm_reg<32, 32, 50, 10, false><<<(NN + 255) / 256, 256, 0, stream>>>(h2, predW, predb, out, NN);
}

// Round 5
// 965.271 us; speedup vs baseline: 1.1285x; 1.1285x over previous
//
#include <hip/hip_runtime.h>
#include <hip/hip_fp16.h>
#include <cstdint>
#include <cstddef>

#define NN 100000
#define NE 1600000
#define NEP (NE + NN)   // edges + self-loops = 1,700,000
#define SCAN_BLOCKS ((NN + 1023) / 1024)   // 98
#define XSTR 68         // padded stride for x (16-B aligned rows)

__device__ __forceinline__ float elu_f(float x) {
    return x > 0.f ? x : __expf(x) - 1.f;
}

// DPP row_ror add: x + rotate_within_row16(x, N). Pure VALU, no LDS pipe.
template<int N>
__device__ __forceinline__ float rrot_add(float x) {
    int s = __builtin_amdgcn_update_dpp(0, __float_as_int(x), 0x120 | N, 0xF, 0xF, true);
    return x + __int_as_float(s);
}
// full sum over each 16-lane row, result in all 16 lanes
__device__ __forceinline__ float row16_allsum(float x) {
    x = rrot_add<1>(x);
    x = rrot_add<2>(x);
    x = rrot_add<4>(x);
    x = rrot_add<8>(x);
    return x;
}

// ================= CSR build (counting sort by dst) =================

__global__ __launch_bounds__(256) void count_deg(const int* __restrict__ ei, int* __restrict__ deg)
{
    int e = blockIdx.x * 256 + threadIdx.x;
    if (e >= NEP) return;
    int dst = (e < NE) ? ei[NE + e] : e - NE;
    atomicAdd(&deg[dst], 1);
}

__global__ __launch_bounds__(256) void scan_pass1(const int* __restrict__ deg, int* __restrict__ part)
{
    __shared__ int wsum[4];
    int t = threadIdx.x;
    int i0 = blockIdx.x * 1024 + t * 4;
    int s = 0;
    if (i0 + 3 < NN) { int4 d = *(const int4*)(deg + i0); s = d.x + d.y + d.z + d.w; }
    else {
        for (int k = 0; k < 4; k++) if (i0 + k < NN) s += deg[i0 + k];
    }
    for (int d = 1; d < 64; d <<= 1) s += __shfl_xor(s, d, 64);
    if ((t & 63) == 0) wsum[t >> 6] = s;
    __syncthreads();
    if (t == 0) part[blockIdx.x] = wsum[0] + wsum[1] + wsum[2] + wsum[3];
}

__global__ __launch_bounds__(128) void scan_pass2(int* __restrict__ part, int* __restrict__ off)
{
    __shared__ int wt[2];
    int t = threadIdx.x;
    int lane = t & 63, w = t >> 6;
    int v = (t < SCAN_BLOCKS) ? part[t] : 0;
    int x = v;
    for (int d = 1; d < 64; d <<= 1) { int y = __shfl_up(x, d, 64); if (lane >= d) x += y; }
    if (lane == 63) wt[w] = x;
    __syncthreads();
    int base = (w == 1) ? wt[0] : 0;
    int excl = base + x - v;
    if (t < SCAN_BLOCKS) part[t] = excl;
    if (t == SCAN_BLOCKS - 1) off[NN] = excl + v;
}

__global__ __launch_bounds__(256) void scan_pass3(const int* __restrict__ deg, const int* __restrict__ part,
                                                  int* __restrict__ off, int* __restrict__ cursor)
{
    __shared__ int wsum[4];
    int t = threadIdx.x, lane = t & 63, w = t >> 6;
    int i0 = blockIdx.x * 1024 + t * 4;
    int d0 = 0, d1 = 0, d2 = 0, d3 = 0;
    if (i0 + 3 < NN) { int4 d = *(const int4*)(deg + i0); d0 = d.x; d1 = d.y; d2 = d.z; d3 = d.w; }
    else if (i0 < NN) {
        d0 = deg[i0];
        if (i0 + 1 < NN) d1 = deg[i0 + 1];
        if (i0 + 2 < NN) d2 = deg[i0 + 2];
    }
    int s = d0 + d1 + d2 + d3;
    int x = s;
    for (int d = 1; d < 64; d <<= 1) { int y = __shfl_up(x, d, 64); if (lane >= d) x += y; }
    if (lane == 63) wsum[w] = x;
    __syncthreads();
    int wbase = 0;
    for (int i = 0; i < w; i++) wbase += wsum[i];
    int base = part[blockIdx.x] + wbase + x - s;
    if (i0 < NN)     { off[i0]     = base;                cursor[i0]     = base; }
    if (i0 + 1 < NN) { off[i0 + 1] = base + d0;           cursor[i0 + 1] = base + d0; }
    if (i0 + 2 < NN) { off[i0 + 2] = base + d0 + d1;      cursor[i0 + 2] = base + d0 + d1; }
    if (i0 + 3 < NN) { off[i0 + 3] = base + d0 + d1 + d2; cursor[i0 + 3] = base + d0 + d1 + d2; }
}

__global__ __launch_bounds__(256) void scatter_csr(const int* __restrict__ ei,
                                                   int* __restrict__ cursor, int* __restrict__ csr)
{
    int e = blockIdx.x * 256 + threadIdx.x;
    if (e >= NEP) return;
    int src, dst;
    if (e < NE) { src = ei[e]; dst = ei[NE + e]; } else { src = dst = e - NE; }
    int pos = atomicAdd(&cursor[dst], 1);
    csr[pos] = src;
}

// ================= node feature prep (LDS-staged weights, measured-good) =================

__global__ __launch_bounds__(256) void bio_kernel(
    const float* __restrict__ xb, const float* __restrict__ W1, const float* __restrict__ b1,
    const float* __restrict__ g0, const float* __restrict__ bb0,
    const float* __restrict__ m0, const float* __restrict__ v0,
    const float* __restrict__ W2, const float* __restrict__ b2,
    float* __restrict__ x)
{
    __shared__ float sW1[16*64], sW2[16*16], sb1[16], sb2[16], ss[16], st[16];
    int tid = threadIdx.x;
    for (int idx = tid; idx < 1024; idx += 256) sW1[idx] = W1[idx];
    if (tid < 256) sW2[tid] = W2[tid];
    if (tid < 16) {
        sb1[tid] = b1[tid]; sb2[tid] = b2[tid];
        float s = g0[tid] * rsqrtf(v0[tid] + 1e-5f);
        ss[tid] = s; st[tid] = bb0[tid] - m0[tid] * s;
    }
    __syncthreads();
    int i = blockIdx.x * 256 + tid;
    if (i >= NN) return;
    float bio[64];
    const float4* p = (const float4*)(xb + (size_t)i * 64);
    #pragma unroll
    for (int q = 0; q < 16; q++) {
        float4 f = p[q];
        bio[q*4] = f.x; bio[q*4+1] = f.y; bio[q*4+2] = f.z; bio[q*4+3] = f.w;
    }
    float t1[16];
    #pragma unroll
    for (int j = 0; j < 16; j++) {
        float acc = sb1[j];
        #pragma unroll
        for (int k = 0; k < 64; k++) acc += bio[k] * sW1[j*64 + k];
        acc = acc * ss[j] + st[j];
        t1[j] = elu_f(acc);
    }
    float* xo = x + (size_t)i * XSTR + 50;
    #pragma unroll
    for (int j = 0; j < 16; j++) {
        float acc = sb2[j];
        #pragma unroll
        for (int k = 0; k < 16; k++) acc += t1[k] * sW2[j*16 + k];
        xo[j] = elu_f(acc);
    }
}

__global__ __launch_bounds__(256) void copy_pca(const float* __restrict__ xp, float* __restrict__ x)
{
    int t = blockIdx.x * 256 + threadIdx.x;
    if (t >= NN * 50) return;
    int i = t / 50, j = t - i * 50;
    x[(size_t)i * XSTR + j] = xp[t];
}

// ================= row-tiled GEMM (LDS-staged; fp16 or fp32 out) =================

template<int DIN, int DSTR, int DOUT, int NPB, bool HOUT>
__global__ __launch_bounds__(256) void gemm_rowtile(
    const float* __restrict__ in, const float* __restrict__ W,
    const float* __restrict__ bias, void* __restrict__ outv, int n)
{
    constexpr int GROUPS = 256 / DOUT;
    constexpr int RPT = NPB / GROUPS;
    __shared__ float sW[DOUT * DIN];
    __shared__ float sx[NPB * DIN];
    __shared__ float sb[DOUT];
    int tid = threadIdx.x;
    for (int idx = tid; idx < DOUT * DIN; idx += 256) sW[idx] = W[idx];
    if (tid < DOUT) sb[tid] = bias[tid];
    int node0 = blockIdx.x * NPB;
    for (int idx = tid; idx < NPB * DIN; idx += 256) {
        int r = idx / DIN, c = idx - r * DIN;
        int i = node0 + r;
        sx[idx] = (i < n) ? in[(size_t)i * DSTR + c] : 0.f;
    }
    __syncthreads();
    int j = tid % DOUT;
    int g = tid / DOUT;
    float acc[RPT];
    #pragma unroll
    for (int r = 0; r < RPT; r++) acc[r] = sb[j];
    for (int k = 0; k < DIN; k++) {
        float w = sW[j * DIN + k];
        #pragma unroll
        for (int r = 0; r < RPT; r++) acc[r] += sx[(g * RPT + r) * DIN + k] * w;
    }
    #pragma unroll
    for (int r = 0; r < RPT; r++) {
        int i = node0 + g * RPT + r;
        if (i < n) {
            if (HOUT) ((__half*)outv)[(size_t)i * DOUT + j] = __float2half(acc[r]);
            else      ((float*)outv)[(size_t)i * DOUT + j] = acc[r];
        }
    }
}

// ================= fused GATv2 layer 1: one wave per dst node =================
// lane = channel-pair (128 ch). src broadcast via readlane (scalar addr),
// 16-lane head reduction via DPP row_ror.
__global__ __launch_bounds__(256) void fused_gat1(
    const int* __restrict__ off, const int* __restrict__ csr,
    const __half* __restrict__ xl, const __half* __restrict__ xr,
    const float* __restrict__ att, const float* __restrict__ bias,
    const float* __restrict__ g, const float* __restrict__ b,
    const float* __restrict__ m, const float* __restrict__ v,
    float* __restrict__ h1)
{
    int wave = threadIdx.x >> 6;
    int lane = threadIdx.x & 63;
    int node = blockIdx.x * 4 + wave;
    if (node >= NN) return;
    int ch = lane * 2;

    float2 xrv = __half22float2(*(const __half2*)(xr + (size_t)node * 128 + ch));
    float2 av  = *(const float2*)(att + ch);

    int k0 = off[node], k1 = off[node + 1];
    float accx = 0.f, accy = 0.f, denom = 0.f;

    for (int base = k0; base < k1; base += 64) {
        int nb = min(64, k1 - base);
        int mysrc = (lane < nb) ? csr[base + lane] : 0;
        int cs = __builtin_amdgcn_readlane(mysrc, 0);   // scalar
        __half2 hcur = *((const __half2*)xl + (size_t)cs * 64 + lane);
        for (int t = 0; t < nb; t++) {
            int tn = (t + 1 < nb) ? t + 1 : t;
            int ns = __builtin_amdgcn_readlane(mysrc, tn);  // scalar
            __half2 hnxt = *((const __half2*)xl + (size_t)ns * 64 + lane);
            float2 xlv = __half22float2(hcur);
            float sx = xlv.x + xrv.x; sx = fmaxf(sx, 0.2f * sx);
            float sy = xlv.y + xrv.y; sy = fmaxf(sy, 0.2f * sy);
            float pp = sx * av.x + sy * av.y;
            pp = row16_allsum(pp);          // per-head (16-lane) dot
            float w = __expf(pp);
            denom += w;
            accx = fmaf(xlv.x, w, accx);
            accy = fmaf(xlv.y, w, accy);
            hcur = hnxt;
        }
    }
    float inv = 1.f / (denom + 1e-16f);
    float sX = g[ch]     * rsqrtf(v[ch]     + 1e-5f);
    float sY = g[ch + 1] * rsqrtf(v[ch + 1] + 1e-5f);
    float ox = accx * inv + bias[ch];
    float oy = accy * inv + bias[ch + 1];
    ox = ox * sX + (b[ch]     - m[ch]     * sX);
    oy = oy * sY + (b[ch + 1] - m[ch + 1] * sY);
    float2 o; o.x = elu_f(ox); o.y = elu_f(oy);
    *(float2*)(h1 + (size_t)node * 128 + ch) = o;
}

// ================= fused GATv2 layer 2: one wave per dst node =================
// 64 lanes = 4 edge-slots (rows of 16) x 16 channel-pairs (32 ch).
// Per-edge logit reduce = DPP row_ror within the 16-lane row; 4 edges/iter.
__global__ __launch_bounds__(256) void fused_gat2(
    const int* __restrict__ off, const int* __restrict__ csr,
    const __half* __restrict__ xl, const __half* __restrict__ xr,
    const float* __restrict__ att, const float* __restrict__ bias,
    const float* __restrict__ g, const float* __restrict__ b,
    const float* __restrict__ m, const float* __restrict__ v,
    float* __restrict__ h2)
{
    int wave = threadIdx.x >> 6;
    int lane = threadIdx.x & 63;
    int node = blockIdx.x * 4 + wave;
    if (node >= NN) return;
    int row = lane >> 4;      // edge slot 0..3
    int cp  = lane & 15;      // channel pair
    int c   = cp * 2;

    float2 xrv = __half22float2(*(const __half2*)(xr + (size_t)node * 32 + c));
    float2 av  = *(const float2*)(att + c);

    int k0 = off[node], k1 = off[node + 1];
    float accx = 0.f, accy = 0.f, denom = 0.f;

    for (int base = k0; base < k1; base += 64) {
        int nb = min(64, k1 - base);
        int mysrc = (lane < nb) ? csr[base + lane] : 0;
        for (int t = 0; t < nb; t += 4) {
            int i1 = min(t + 1, nb - 1), i2 = min(t + 2, nb - 1), i3 = min(t + 3, nb - 1);
            int s0 = __builtin_amdgcn_readlane(mysrc, t);
            int s1 = __builtin_amdgcn_readlane(mysrc, i1);
            int s2 = __builtin_amdgcn_readlane(mysrc, i2);
            int s3 = __builtin_amdgcn_readlane(mysrc, i3);
            int sa = (row & 1) ? s1 : s0;
            int sb_ = (row & 1) ? s3 : s2;
            int ss = (row & 2) ? sb_ : sa;
            __half2 hv = *((const __half2*)xl + (size_t)ss * 16 + cp);
            float2 xlv = __half22float2(hv);
            float sx = xlv.x + xrv.x; sx = fmaxf(sx, 0.2f * sx);
            float sy = xlv.y + xrv.y; sy = fmaxf(sy, 0.2f * sy);
            float pp = sx * av.x + sy * av.y;
            pp = row16_allsum(pp);          // per-edge 32-ch dot
            bool valid = (t + row) < nb;
            float w = valid ? __expf(pp) : 0.f;
            denom += w;
            accx = fmaf(xlv.x, w, accx);
            accy = fmaf(xlv.y, w, accy);
        }
    }
    // combine the 4 edge slots (lanes differing in bits 4,5)
    accx  += __shfl_xor(accx, 16, 64);  accx  += __shfl_xor(accx, 32, 64);
    accy  += __shfl_xor(accy, 16, 64);  accy  += __shfl_xor(accy, 32, 64);
    denom += __shfl_xor(denom, 16, 64); denom += __shfl_xor(denom, 32, 64);
    if (row == 0) {
        float inv = 1.f / (denom + 1e-16f);
        float sC0 = g[c]     * rsqrtf(v[c]     + 1e-5f);
        float sC1 = g[c + 1] * rsqrtf(v[c + 1] + 1e-5f);
        float o0 = accx * inv + bias[c];
        float o1 = accy * inv + bias[c + 1];
        o0 = o0 * sC0 + (b[c]     - m[c]     * sC0);
        o1 = o1 * sC1 + (b[c + 1] - m[c + 1] * sC1);
        float2 o; o.x = elu_f(o0); o.y = elu_f(o1);
        *(float2*)(h2 + (size_t)node * 32 + c) = o;
    }
}

// ================= prediction head: Linear(32,50) =================

__global__ __launch_bounds__(256) void predk(
    const float* __restrict__ h, const float* __restrict__ W,
    const float* __restrict__ bias, float* __restrict__ out)
{
    __shared__ float sW[50 * 32];
    __shared__ float sb[50];
    int tid = threadIdx.x;
    for (int idx = tid; idx < 1600; idx += 256) sW[idx] = W[idx];
    if (tid < 50) sb[tid] = bias[tid];
    __syncthreads();
    int t = blockIdx.x * 256 + tid;
    if (t >= NN * 50) return;
    int i = t / 50, j = t - i * 50;
    const float* hr = h + (size_t)i * 32;
    float acc = sb[j];
    #pragma unroll
    for (int k = 0; k < 32; k++) acc += hr[k] * sW[j * 32 + k];
    out[t] = acc;
}

extern "C" void kernel_launch(void* const* d_in, const int* in_sizes, int n_in,
                              void* d_out, int out_size, void* d_ws, size_t ws_size,
                              hipStream_t stream)
{
    const float* x_pca = (const float*)d_in[0];
    const float* x_bio = (const float*)d_in[1];
    const int*   ei    = (const int*)d_in[2];
    const float* bioW1 = (const float*)d_in[3];
    const float* biob1 = (const float*)d_in[4];
    const float* bn0_g = (const float*)d_in[5];
    const float* bn0_b = (const float*)d_in[6];
    const float* bn0_m = (const float*)d_in[7];
    const float* bn0_v = (const float*)d_in[8];
    const float* bioW2 = (const float*)d_in[9];
    const float* biob2 = (const float*)d_in[10];
    const float* Wl1   = (const float*)d_in[11];
    const float* bl1   = (const float*)d_in[12];
    const float* Wr1   = (const float*)d_in[13];
    const float* br1   = (const float*)d_in[14];
    const float* att1  = (const float*)d_in[15];
    const float* bias1 = (const float*)d_in[16];
    const float* bn1_g = (const float*)d_in[17];
    const float* bn1_b = (const float*)d_in[18];
    const float* bn1_m = (const float*)d_in[19];
    const float* bn1_v = (const float*)d_in[20];
    const float* Wl2   = (const float*)d_in[21];
    const float* bl2   = (const float*)d_in[22];
    const float* Wr2   = (const float*)d_in[23];
    const float* br2   = (const float*)d_in[24];
    const float* att2  = (const float*)d_in[25];
    const float* bias2 = (const float*)d_in[26];
    const float* bn2_g = (const float*)d_in[27];
    const float* bn2_b = (const float*)d_in[28];
    const float* bn2_m = (const float*)d_in[29];
    const float* bn2_v = (const float*)d_in[30];
    const float* predW = (const float*)d_in[31];
    const float* predb = (const float*)d_in[32];

    float* ws = (float*)d_ws;
    float*  x    = ws;                                  // N*68 floats
    float*  h1   = x + (size_t)NN * XSTR;               // N*128 floats
    __half* xl1h = (__half*)(h1 + (size_t)NN * 128);    // N*128 halves
    __half* xr1h = xl1h + (size_t)NN * 128;             // N*128 halves
    __half* xl2h = xr1h + (size_t)NN * 128;             // N*32 halves
    __half* xr2h = xl2h + (size_t)NN * 32;              // N*32 halves
    float*  h2   = (float*)(xr2h + (size_t)NN * 32);    // N*32 floats
    int*    ibase  = (int*)(h2 + (size_t)NN * 32);
    int*    deg    = ibase;            // NN
    int*    off    = ibase + NN;       // NN+1
    int*    cursor = off + NN + 1;     // NN
    int*    part   = cursor + NN;      // 128
    int*    csr    = part + 128;       // NEP

    float* out = (float*)d_out;

    // ---- CSR build ----
    hipMemsetAsync(deg, 0, (size_t)NN * sizeof(int), stream);
    count_deg<<<(NEP + 255) / 256, 256, 0, stream>>>(ei, deg);
    scan_pass1<<<SCAN_BLOCKS, 256, 0, stream>>>(deg, part);
    scan_pass2<<<1, 128, 0, stream>>>(part, off);
    scan_pass3<<<SCAN_BLOCKS, 256, 0, stream>>>(deg, part, off, cursor);
    scatter_csr<<<(NEP + 255) / 256, 256, 0, stream>>>(ei, cursor, csr);

    // ---- node features ----
    bio_kernel<<<(NN + 255) / 256, 256, 0, stream>>>(
        x_bio, bioW1, biob1, bn0_g, bn0_b, bn0_m, bn0_v, bioW2, biob2, x);
    copy_pca<<<(NN * 50 + 255) / 256, 256, 0, stream>>>(x_pca, x);

    // ---- layer-1 transforms (fp16 out) ----
    gemm_rowtile<66, XSTR, 128, 16, true><<<(NN + 15) / 16, 256, 0, stream>>>(x, Wl1, bl1, xl1h, NN);
    gemm_rowtile<66, XSTR, 128, 16, true><<<(NN + 15) / 16, 256, 0, stream>>>(x, Wr1, br1, xr1h, NN);

    // ---- fused layer-1 edge phase + bias/BN/ELU ----
    fused_gat1<<<(NN + 3) / 4, 256, 0, stream>>>(
        off, csr, xl1h, xr1h, att1, bias1, bn1_g, bn1_b, bn1_m, bn1_v, h1);

    // ---- layer-2 transforms (fp16 out) ----
    gemm_rowtile<128, 128, 32, 16, true><<<(NN + 15) / 16, 256, 0, stream>>>(h1, Wl2, bl2, xl2h, NN);
    gemm_rowtile<128, 128, 32, 16, true><<<(NN + 15) / 16, 256, 0, stream>>>(h1, Wr2, br2, xr2h, NN);

    // ---- fused layer-2 edge phase + bias/BN/ELU ----
    fused_gat2<<<(NN + 3) / 4, 256, 0, stream>>>(
        off, csr, xl2h, xr2h, att2, bias2, bn2_g, bn2_b, bn2_m, bn2_v, h2);

    // ---- prediction head ----
    predk<<<(NN * 50 + 255) / 256, 256, 0, stream>>>(h2, predW, predb, out);
}